// Round 2
// 624.296 us; speedup vs baseline: 1.1017x; 1.1017x over previous
//
#include <hip/hip_runtime.h>
#include <stdint.h>

// XCiT cross-covariance attention, bf16-MFMA pipeline. R5 (= R4 resubmit + rule-18 hardening):
//  - GEMMs on the 256x256 / BK=64 / 8-wave 8-phase template
//    (T2 LDS XOR-swizzle via pre-swizzled global source, T3/T4 counted
//    vmcnt(6) deep pipeline with raw s_barrier, T5 setprio around MFMA).
//  - attn: unchanged (k-split x16 partial + finalize + av MFMA).
//
// ws layout (u16 elems unless noted):
//   xbf   [8][4096][1024]                33,554,432   @ 0
//   wbf   [4][1024][1024] (q,k,v,o)       4,194,304   @ 33,554,432
//   qk    [2][8][1024][4096] (Q,K ch-major) 67,108,864 @ 37,748,736
//   vt    [8][4096][1024] (V token-major) 33,554,432  @ 104,857,600
//   attnP fp32 [16][128][64][64]          8,388,608 f @ byte 276,824,064
//   nsqP  fp32 [16][128][2][64]             262,144 f
//   attnb bf16 [128][64][64]                524,288
//   outb  aliases qk (Q,K dead after attn_partial)    @ 37,748,736

typedef unsigned short u16;
typedef __attribute__((ext_vector_type(8))) short bf16x8;
typedef __attribute__((ext_vector_type(8))) u16 u16x8;
typedef __attribute__((ext_vector_type(4))) u16 u16x4;
typedef __attribute__((ext_vector_type(4))) float f32x4;

__device__ __forceinline__ float bf2f(u16 u) {
  union { unsigned int i; float f; } x;
  x.i = ((unsigned int)u) << 16;
  return x.f;
}
__device__ __forceinline__ u16 f2bf(float f) {  // RNE, inputs finite
  union { float f; unsigned int i; } x;
  x.f = f;
  unsigned int u = x.i;
  u = u + 0x7fffu + ((u >> 16) & 1u);
  return (u16)(u >> 16);
}

// async global->LDS, 16B/lane; LDS dest is wave-uniform base + lane*16.
__device__ __forceinline__ void gload16(const u16* g, u16* l) {
  __builtin_amdgcn_global_load_lds(
      (const __attribute__((address_space(1))) void*)g,
      (__attribute__((address_space(3))) void*)l, 16, 0, 0);
}

// ---------------- cast fp32 -> bf16 (x and the 4 weight matrices) ----------------
__global__ __launch_bounds__(256) void cast_kernel(
    const float4* __restrict__ x, const float4* __restrict__ wq,
    const float4* __restrict__ wk, const float4* __restrict__ wv,
    const float4* __restrict__ wo, u16x4* __restrict__ xbf,
    u16x4* __restrict__ wbf) {
  long i = (long)blockIdx.x * 256 + threadIdx.x;  // float4 index; covers 8388608
  float4 v = x[i];
  u16x4 o;
  o[0] = f2bf(v.x); o[1] = f2bf(v.y); o[2] = f2bf(v.z); o[3] = f2bf(v.w);
  xbf[i] = o;
  if (i < 1048576) {  // 4 weights x 262144 float4s
    int sel = (int)(i >> 18);
    const float4* s = (sel == 0) ? wq : (sel == 1) ? wk : (sel == 2) ? wv : wo;
    float4 w = s[i & 262143];
    u16x4 ow;
    ow[0] = f2bf(w.x); ow[1] = f2bf(w.y); ow[2] = f2bf(w.z); ow[3] = f2bf(w.w);
    wbf[i] = ow;
  }
}

// ---------------- 256x256 NT bf16 MFMA GEMM, K=1024, 8-phase pipeline ----------------
// C[m,n] = sum_k A[m,k]*B[n,k].  lda = ldb = 1024 in all modes.
// MODE 0: Q,K proj (z=w*8+b): A=W[w](1024xK), B=x[b](4096xK), C bf16 ld 4096
// MODE 1: out proj (z=b): A=outb[b](4096xK), B=Wo(1024xK), C fp32 ld 1024 + bias
// MODE 2: V proj   (z=b): A=x[b](4096xK), B=Wv(1024xK), C bf16 ld 1024
//
// 512 threads = 8 waves (2 M x 4 N); per-wave C = 128x64; acc[8][4] f32x4.
// LDS 128 KiB: double-buffered A/B tiles [256][64] bf16, XOR-swizzled:
//   u16 idx ^= (row&7)<<3  (byte ^= (row&7)<<4) -- kills the stride-128B
//   16-way ds_read_b128 bank conflict. global_load_lds writes linearly, so
//   the swizzle is applied by permuting each lane's GLOBAL source slot.
// Per K-tile: 4 phases; half-tile staging stream B0,B1,A0,A1; tile t stages
//   (t+1,A1) @p0, (t+2,B0) @p1, (t+2,B1) @p2, (t+2,A0) @p3.  Region death:
//   all B-frag reads in p0, A-qr0 in p0, A-qr1 in p2 -> each region is fully
//   read (lgkmcnt(0)+barrier) before its overwriting stage is issued.
//   s_waitcnt vmcnt(6) once per tile (never 0 in steady state) guarantees
//   tile t+1 fully landed (its newest half-tile is 4th-newest = outside the
//   3-half-tile / 6-load window).
// Deadlock-free by construction: all s_barrier in wave-uniform control flow;
// waitcnts always retire.

#define STG(Lb, G, r0, kt)                                                   \
  gload16((G) + (long)((r0) + rl) * 1024 + (kt) * 64 + slswz,                \
          (Lb) + (r0) * 64 + tid * 8)

#define LDB(Bb)                                                              \
  _Pragma("unroll") for (int jj = 0; jj < 4; ++jj)                           \
  _Pragma("unroll") for (int ks = 0; ks < 2; ++ks) {                         \
    const int idx = (wc * 64 + jj * 16 + fm) * 64 + ks * 32 + fk;            \
    bfr[jj][ks] = *(const bf16x8*)((Bb) + (idx ^ swz));                      \
  }

#define LDA(Ab, qr)                                                          \
  _Pragma("unroll") for (int i = 0; i < 4; ++i)                              \
  _Pragma("unroll") for (int ks = 0; ks < 2; ++ks) {                         \
    const int idx = (wr * 128 + (qr)*64 + i * 16 + fm) * 64 + ks * 32 + fk;  \
    afr[i][ks] = *(const bf16x8*)((Ab) + (idx ^ swz));                       \
  }

#define MM(qr, qc)                                                           \
  {                                                                          \
    __builtin_amdgcn_s_setprio(1);                                           \
    _Pragma("unroll") for (int ks = 0; ks < 2; ++ks)                         \
    _Pragma("unroll") for (int i = 0; i < 4; ++i)                            \
    _Pragma("unroll") for (int jj = 0; jj < 2; ++jj)                         \
        acc[(qr)*4 + i][(qc)*2 + jj] =                                       \
            __builtin_amdgcn_mfma_f32_16x16x32_bf16(                         \
                afr[i][ks], bfr[(qc)*2 + jj][ks],                            \
                acc[(qr)*4 + i][(qc)*2 + jj], 0, 0, 0);                      \
    __builtin_amdgcn_s_setprio(0);                                           \
  }

#define LGKM0                                        \
  do {                                               \
    asm volatile("s_waitcnt lgkmcnt(0)" ::: "memory"); \
    __builtin_amdgcn_sched_barrier(0);               \
  } while (0)
#define VM6 asm volatile("s_waitcnt vmcnt(6)" ::: "memory")
#define VM0 asm volatile("s_waitcnt vmcnt(0)" ::: "memory")
#define VMNONE (void)0
#define BAR __builtin_amdgcn_s_barrier()

#define TILE(Ab, Bb, Aoth, kt, S1, S2, VMW)                                  \
  {                                                                          \
    /* p0: read all B + A(qr0); stage (kt+1, A1) into other A buffer */      \
    LDB(Bb);                                                                 \
    LDA(Ab, 0);                                                              \
    if (S1) { STG(Aoth, Ag, 128, (kt) + 1); STG(Aoth, Ag, 192, (kt) + 1); }  \
    BAR;                                                                     \
    MM(0, 0);                                                                \
    LGKM0;                                                                   \
    BAR;                                                                     \
    /* p1: stage (kt+2, B0) over this tile's dead B0 region */               \
    if (S2) { STG(Bb, Bg, 0, (kt) + 2); STG(Bb, Bg, 64, (kt) + 2); }         \
    BAR;                                                                     \
    MM(0, 1);                                                                \
    BAR;                                                                     \
    /* p2: read A(qr1); stage (kt+2, B1) */                                  \
    LDA(Ab, 1);                                                              \
    if (S2) { STG(Bb, Bg, 128, (kt) + 2); STG(Bb, Bg, 192, (kt) + 2); }      \
    BAR;                                                                     \
    MM(1, 0);                                                                \
    LGKM0;                                                                   \
    BAR;                                                                     \
    /* p3: stage (kt+2, A0) */                                               \
    if (S2) { STG(Ab, Ag, 0, (kt) + 2); STG(Ab, Ag, 64, (kt) + 2); }         \
    BAR;                                                                     \
    MM(1, 1);                                                                \
    VMW;                                                                     \
    BAR;                                                                     \
  }

template <int MODE>
__global__ __launch_bounds__(512, 2) void gemm256(const u16* __restrict__ A,
                                                  const u16* __restrict__ B,
                                                  void* __restrict__ C,
                                                  const float* __restrict__ bias) {
  __shared__ u16 As0[16384];
  __shared__ u16 As1[16384];
  __shared__ u16 Bs0[16384];
  __shared__ u16 Bs1[16384];
  const int tid = threadIdx.x;
  const int lane = tid & 63;
  const int wave = tid >> 6;
  const int wr = wave >> 2;  // 0..1 -> rows [wr*128, +128)
  const int wc = wave & 3;   // 0..3 -> cols [wc*64, +64)
  const int m0 = blockIdx.y * 256;
  const int n0 = blockIdx.x * 256;

  long aoff, boff, coff;
  if (MODE == 0) {
    int w = blockIdx.z >> 3;
    int b = blockIdx.z & 7;
    aoff = (long)w * 1048576;
    boff = (long)b * 4194304;
    coff = (long)blockIdx.z * 4194304;
  } else {
    aoff = (long)blockIdx.z * 4194304;
    boff = 0;
    coff = (long)blockIdx.z * 4194304;
  }
  const u16* Ag = A + aoff + (long)m0 * 1024;
  const u16* Bg = B + boff + (long)n0 * 1024;

  // staging decomposition: one STG = 512 lanes x 16B = 64 rows; per-thread
  // row rl, linear lds slot (tid&7); global slot pre-swizzled by row.
  const int rl = tid >> 3;
  const int slswz = ((tid & 7) ^ (rl & 7)) * 8;
  // fragment read decomposition
  const int fm = lane & 15;
  const int fk = (lane >> 4) << 3;
  const int swz = (fm & 7) << 3;  // u16-idx XOR; row&7 == fm&7 for all rows used

  f32x4 acc[8][4];
  const f32x4 z4 = {0.f, 0.f, 0.f, 0.f};
#pragma unroll
  for (int i = 0; i < 8; i++)
#pragma unroll
    for (int j = 0; j < 4; j++) acc[i][j] = z4;

  bf16x8 afr[4][2], bfr[4][2];

  // prologue: tile0 -> buf0 (B0,B1,A0,A1), tile1 -> buf1 (B0,B1,A0); 14 loads.
  STG(Bs0, Bg, 0, 0);   STG(Bs0, Bg, 64, 0);
  STG(Bs0, Bg, 128, 0); STG(Bs0, Bg, 192, 0);
  STG(As0, Ag, 0, 0);   STG(As0, Ag, 64, 0);
  STG(As0, Ag, 128, 0); STG(As0, Ag, 192, 0);
  STG(Bs1, Bg, 0, 1);   STG(Bs1, Bg, 64, 1);
  STG(Bs1, Bg, 128, 1); STG(Bs1, Bg, 192, 1);
  STG(As1, Ag, 0, 1);   STG(As1, Ag, 64, 1);
  VM6;  // oldest 8 (= all of tile 0) complete
  BAR;

#pragma unroll 1
  for (int it = 0; it < 7; ++it) {
    TILE(As0, Bs0, As1, 2 * it, true, true, VM6);
    TILE(As1, Bs1, As0, 2 * it + 1, true, true, VM6);
  }
  TILE(As0, Bs0, As1, 14, true, false, VM0);   // stages (15,A1) only; drain
  TILE(As1, Bs1, As0, 15, false, false, VMNONE);

  // epilogue
  const int rq = (lane >> 4) * 4;
  const int mBase = m0 + wr * 128;
  const int nBase = n0 + wc * 64;
  if (MODE == 1) {
    float* Cf = (float*)C + coff;
#pragma unroll
    for (int jj = 0; jj < 4; ++jj) {
      float bv = bias[nBase + jj * 16 + fm];
#pragma unroll
      for (int i = 0; i < 8; ++i)
#pragma unroll
        for (int r = 0; r < 4; ++r) {
          int m = mBase + i * 16 + rq + r;
          int n = nBase + jj * 16 + fm;
          Cf[(long)m * 1024 + n] = acc[i][jj][r] + bv;
        }
    }
  } else {
    const int ldc = (MODE == 0) ? 4096 : 1024;
    u16* Cb = (u16*)C + coff;
#pragma unroll
    for (int i = 0; i < 8; ++i)
#pragma unroll
      for (int jj = 0; jj < 4; ++jj)
#pragma unroll
        for (int r = 0; r < 4; ++r) {
          int m = mBase + i * 16 + rq + r;
          int n = nBase + jj * 16 + fm;
          Cb[(long)m * ldc + n] = f2bf(acc[i][jj][r]);
        }
  }
}

// ---------------- attn partial: per (bh, kslice-of-4) block; 16 wave-slices ----------------
// Each wave owns 256 k, computes full 64x64 partial S + row sumsq, writes to ws.
__global__ __launch_bounds__(256) void attn_partial(const u16* __restrict__ qk,
                                                    float* __restrict__ attnP,
                                                    float* __restrict__ nsqP) {
  const int bh = blockIdx.x;
  const int b = bh >> 4, h = bh & 15;
  const int tid = threadIdx.x, lane = tid & 63, wave = tid >> 6;
  const int sl = blockIdx.y * 4 + wave;  // 0..15
  const u16* Qg = qk + (long)b * 4194304 + (long)h * 64 * 4096;
  const u16* Kg = Qg + 33554432L;

  const int fm = lane & 15;
  const long kbase = (long)sl * 256 + (lane >> 4) * 8;

  f32x4 acc[4][4];
  const f32x4 z4 = {0.f, 0.f, 0.f, 0.f};
#pragma unroll
  for (int i = 0; i < 4; i++)
#pragma unroll
    for (int j = 0; j < 4; j++) acc[i][j] = z4;
  float sk[4] = {0.f, 0.f, 0.f, 0.f}, sq[4] = {0.f, 0.f, 0.f, 0.f};

  for (int kt = 0; kt < 256; kt += 32) {
    bf16x8 ak[4], aq[4];
#pragma unroll
    for (int i = 0; i < 4; i++) {
      ak[i] = *(const bf16x8*)(Kg + (long)(i * 16 + fm) * 4096 + kbase + kt);
      aq[i] = *(const bf16x8*)(Qg + (long)(i * 16 + fm) * 4096 + kbase + kt);
    }
#pragma unroll
    for (int i = 0; i < 4; i++) {
      const u16x8 kv = (u16x8)ak[i], qv = (u16x8)aq[i];
#pragma unroll
      for (int e = 0; e < 8; e++) {
        float fkk = bf2f(kv[e]); sk[i] += fkk * fkk;
        float fq = bf2f(qv[e]);  sq[i] += fq * fq;
      }
    }
#pragma unroll
    for (int i = 0; i < 4; i++)
#pragma unroll
      for (int j = 0; j < 4; j++)
        acc[i][j] = __builtin_amdgcn_mfma_f32_16x16x32_bf16(ak[i], aq[j],
                                                            acc[i][j], 0, 0, 0);
  }

#pragma unroll
  for (int i = 0; i < 4; i++) {  // fold the 4 k-chunk lane groups
    sk[i] += __shfl_xor(sk[i], 16); sk[i] += __shfl_xor(sk[i], 32);
    sq[i] += __shfl_xor(sq[i], 16); sq[i] += __shfl_xor(sq[i], 32);
  }
  float* np = nsqP + ((long)sl * 128 + bh) * 128;
  if (lane < 16) {
#pragma unroll
    for (int i = 0; i < 4; i++) {
      np[i * 16 + lane] = sk[i];
      np[64 + i * 16 + lane] = sq[i];
    }
  }
  float* sp = attnP + ((long)sl * 128 + bh) * 4096;
  const int rq = (lane >> 4) * 4;
#pragma unroll
  for (int i = 0; i < 4; i++)
#pragma unroll
    for (int j = 0; j < 4; j++)
#pragma unroll
      for (int r = 0; r < 4; r++)
        sp[(i * 16 + rq + r) * 64 + j * 16 + fm] = acc[i][j][r];
}

// ---------------- finalize: sum 16 partials, norms, softmax -> bf16 ----------------
__global__ __launch_bounds__(128) void attn_finalize(const float* __restrict__ attnP,
                                                     const float* __restrict__ nsqP,
                                                     const float* __restrict__ scale,
                                                     u16* __restrict__ attnb) {
  const int bh = blockIdx.x;
  const int h = bh & 15;
  const int tid = threadIdx.x;
  __shared__ float rn[2][64];
  {
    int which = tid >> 6, row = tid & 63;
    float s = 0.f;
#pragma unroll
    for (int sl = 0; sl < 16; sl++)
      s += nsqP[((long)sl * 128 + bh) * 128 + which * 64 + row];
    rn[which][row] = 1.0f / fmaxf(sqrtf(s), 1e-12f);  // F.normalize eps
  }
  __syncthreads();
  if (tid < 64) {
    const int d = tid;
    float row[64];
#pragma unroll
    for (int e = 0; e < 64; e++) row[e] = 0.f;
    for (int sl = 0; sl < 16; sl++) {
      const float4* p =
          (const float4*)(attnP + ((long)sl * 128 + bh) * 4096 + d * 64);
#pragma unroll
      for (int e4 = 0; e4 < 16; e4++) {
        float4 v = p[e4];
        row[e4 * 4 + 0] += v.x;
        row[e4 * 4 + 1] += v.y;
        row[e4 * 4 + 2] += v.z;
        row[e4 * 4 + 3] += v.w;
      }
    }
    const float rk = rn[0][d] * scale[h];
    float mx = -1e30f;
#pragma unroll
    for (int e = 0; e < 64; e++) {
      row[e] = row[e] * rk * rn[1][e];
      mx = fmaxf(mx, row[e]);
    }
    float sum = 0.f;
#pragma unroll
    for (int e = 0; e < 64; e++) {
      row[e] = __expf(row[e] - mx);
      sum += row[e];
    }
    float inv = 1.0f / sum;
    u16* out = attnb + ((long)bh * 64 + d) * 64;
#pragma unroll
    for (int e = 0; e < 64; e++) out[e] = f2bf(row[e] * inv);
  }
}

// ---------------- av: out[d,n] = sum_e attn[d,e]*Vt[n,e], MFMA K=64 ----------------
__global__ __launch_bounds__(256) void av_mfma(const u16* __restrict__ attnb,
                                               const u16* __restrict__ vt,
                                               u16* __restrict__ outb) {
  const int bh = blockIdx.y;
  const int b = bh >> 4, h = bh & 15;
  const int n0 = blockIdx.x * 256;
  const int tid = threadIdx.x, lane = tid & 63, wave = tid >> 6;
  __shared__ u16 As[64 * 72];  // attn [d][e], pad 64->72 (row stride 144B)
  {
    const u16* src = attnb + (long)bh * 4096 + (tid >> 2) * 64 + (tid & 3) * 16;
    u16x8 v0 = *(const u16x8*)src;
    u16x8 v1 = *(const u16x8*)(src + 8);
    u16* dst = As + (tid >> 2) * 72 + (tid & 3) * 16;
    *(u16x8*)dst = v0;
    *(u16x8*)(dst + 8) = v1;
  }
  __syncthreads();
  const int fm = lane & 15;
  const int fe = (lane >> 4) * 8;
  const u16* Vg = vt + (long)b * 4194304 + h * 64 + fe;

  f32x4 acc[4][4];
  const f32x4 z4 = {0.f, 0.f, 0.f, 0.f};
#pragma unroll
  for (int i = 0; i < 4; i++)
#pragma unroll
    for (int j = 0; j < 4; j++) acc[i][j] = z4;

  bf16x8 af[4][2];
#pragma unroll
  for (int i = 0; i < 4; i++)
#pragma unroll
    for (int ks = 0; ks < 2; ks++)
      af[i][ks] = *(const bf16x8*)&As[(i * 16 + fm) * 72 + fe + ks * 32];

#pragma unroll
  for (int ks = 0; ks < 2; ks++)
#pragma unroll
    for (int j = 0; j < 4; j++) {
      int n = n0 + wave * 64 + j * 16 + fm;
      bf16x8 bf = *(const bf16x8*)(Vg + (long)n * 1024 + ks * 32);
#pragma unroll
      for (int i = 0; i < 4; i++)
        acc[i][j] = __builtin_amdgcn_mfma_f32_16x16x32_bf16(af[i][ks], bf,
                                                            acc[i][j], 0, 0, 0);
    }

  const int rq = (lane >> 4) * 4;
  u16* Ob = outb + ((long)b * 1024 + h * 64) * 4096;
#pragma unroll
  for (int i = 0; i < 4; i++)
#pragma unroll
    for (int j = 0; j < 4; j++)
#pragma unroll
      for (int r = 0; r < 4; r++) {
        int d = i * 16 + rq + r;
        int n = n0 + wave * 64 + j * 16 + fm;
        Ob[(long)d * 4096 + n] = f2bf(acc[i][j][r]);
      }
}

extern "C" void kernel_launch(void* const* d_in, const int* in_sizes, int n_in,
                              void* d_out, int out_size, void* d_ws, size_t ws_size,
                              hipStream_t stream) {
  const float* x = (const float*)d_in[0];
  const float* Wq = (const float*)d_in[1];
  const float* Wk = (const float*)d_in[2];
  const float* Wv = (const float*)d_in[3];
  const float* scale = (const float*)d_in[4];
  const float* Wo = (const float*)d_in[5];
  const float* bo = (const float*)d_in[6];
  float* out = (float*)d_out;

  u16* xbf = (u16*)d_ws;                     // 33,554,432
  u16* wbf = xbf + 33554432;                 //  4,194,304
  u16* qk = wbf + 4194304;                   // 67,108,864 (Q then K, ch-major)
  u16* vt = qk + 67108864;                   // 33,554,432 (token-major V)
  float* attnP = (float*)(vt + 33554432);    //  8,388,608 floats
  float* nsqP = attnP + 8388608;             //    262,144 floats
  u16* attnb = (u16*)(nsqP + 262144);        //    524,288
  u16* outb = qk;                            // alias: Q,K dead after attn_partial

  cast_kernel<<<32768, 256, 0, stream>>>((const float4*)x, (const float4*)Wq,
                                         (const float4*)Wk, (const float4*)Wv,
                                         (const float4*)Wo, (u16x4*)xbf,
                                         (u16x4*)wbf);
  gemm256<0><<<dim3(16, 4, 16), 512, 0, stream>>>(wbf, xbf, (void*)qk, nullptr);
  gemm256<2><<<dim3(4, 16, 8), 512, 0, stream>>>(xbf, wbf + 2 * 1048576,
                                                 (void*)vt, nullptr);
  attn_partial<<<dim3(128, 4), 256, 0, stream>>>(qk, attnP, nsqP);
  attn_finalize<<<128, 128, 0, stream>>>(attnP, nsqP, scale, attnb);
  av_mfma<<<dim3(16, 128), 256, 0, stream>>>(attnb, vt, outb);
  gemm256<1><<<dim3(4, 16, 8), 512, 0, stream>>>(outb, wbf + 3 * 1048576,
                                                 (void*)out, bo);
}

// Round 3
// 609.234 us; speedup vs baseline: 1.1289x; 1.0247x over previous
//
#include <hip/hip_runtime.h>
#include <stdint.h>

// XCiT cross-covariance attention, bf16-MFMA pipeline. R6:
//  - gemm256: balanced 4-phase schedule. Reads per phase 8/8/4/4 (ks-split),
//    16 MFMA per phase, ONE barrier per phase (region lifetimes re-derived),
//    vmcnt(4) once per tile. T2 swizzle + T5 setprio kept.
//  - attn_finalize: rewritten for full-GPU parallelism (256 blocks x 256 thr,
//    8-lane-group shuffle softmax, coalesced float4 reads).
//
// ws layout (u16 elems unless noted):
//   xbf   [8][4096][1024]                33,554,432   @ 0
//   wbf   [4][1024][1024] (q,k,v,o)       4,194,304   @ 33,554,432
//   qk    [2][8][1024][4096] (Q,K ch-major) 67,108,864 @ 37,748,736
//   vt    [8][4096][1024] (V token-major) 33,554,432  @ 104,857,600
//   attnP fp32 [16][128][64][64]          8,388,608 f @ byte 276,824,064
//   nsqP  fp32 [16][128][2][64]             262,144 f
//   attnb bf16 [128][64][64]                524,288
//   outb  aliases qk (Q,K dead after attn_partial)    @ 37,748,736

typedef unsigned short u16;
typedef __attribute__((ext_vector_type(8))) short bf16x8;
typedef __attribute__((ext_vector_type(8))) u16 u16x8;
typedef __attribute__((ext_vector_type(4))) u16 u16x4;
typedef __attribute__((ext_vector_type(4))) float f32x4;

__device__ __forceinline__ float bf2f(u16 u) {
  union { unsigned int i; float f; } x;
  x.i = ((unsigned int)u) << 16;
  return x.f;
}
__device__ __forceinline__ u16 f2bf(float f) {  // RNE, inputs finite
  union { float f; unsigned int i; } x;
  x.f = f;
  unsigned int u = x.i;
  u = u + 0x7fffu + ((u >> 16) & 1u);
  return (u16)(u >> 16);
}

// async global->LDS, 16B/lane; LDS dest is wave-uniform base + lane*16.
__device__ __forceinline__ void gload16(const u16* g, u16* l) {
  __builtin_amdgcn_global_load_lds(
      (const __attribute__((address_space(1))) void*)g,
      (__attribute__((address_space(3))) void*)l, 16, 0, 0);
}

// ---------------- cast fp32 -> bf16 (x and the 4 weight matrices) ----------------
__global__ __launch_bounds__(256) void cast_kernel(
    const float4* __restrict__ x, const float4* __restrict__ wq,
    const float4* __restrict__ wk, const float4* __restrict__ wv,
    const float4* __restrict__ wo, u16x4* __restrict__ xbf,
    u16x4* __restrict__ wbf) {
  long i = (long)blockIdx.x * 256 + threadIdx.x;  // float4 index; covers 8388608
  float4 v = x[i];
  u16x4 o;
  o[0] = f2bf(v.x); o[1] = f2bf(v.y); o[2] = f2bf(v.z); o[3] = f2bf(v.w);
  xbf[i] = o;
  if (i < 1048576) {  // 4 weights x 262144 float4s
    int sel = (int)(i >> 18);
    const float4* s = (sel == 0) ? wq : (sel == 1) ? wk : (sel == 2) ? wv : wo;
    float4 w = s[i & 262143];
    u16x4 ow;
    ow[0] = f2bf(w.x); ow[1] = f2bf(w.y); ow[2] = f2bf(w.z); ow[3] = f2bf(w.w);
    wbf[i] = ow;
  }
}

// ---------------- 256x256 NT bf16 MFMA GEMM, K=1024, balanced 4-phase ----------------
// C[m,n] = sum_k A[m,k]*B[n,k].  lda = ldb = 1024 in all modes.
// MODE 0: Q,K proj (z=w*8+b): A=W[w](1024xK), B=x[b](4096xK), C bf16 ld 4096
// MODE 1: out proj (z=b): A=outb[b](4096xK), B=Wo(1024xK), C fp32 ld 1024 + bias
// MODE 2: V proj   (z=b): A=x[b](4096xK), B=Wv(1024xK), C bf16 ld 1024
//
// 512 threads = 8 waves (2M x 4N); per-wave C = 128x64; acc[8][4] f32x4 (AGPR).
// LDS 128 KiB: double-buffered A/B tiles [256][64] bf16, row-XOR swizzled
// (u16 idx ^= (row&7)<<3) -> 0 bank conflicts (verified R5). global_load_lds
// writes linearly; swizzle applied by permuting each lane's GLOBAL source slot.
//
// Per K-tile, 4 phases x {ds_reads; 2 gload_lds; 16 MFMA; lgkm0; BAR}:
//   p0: read B[all]ks0 (4) + A[qr0]ks0 (4); stage A1(t+1)->S(t+1); MFMA qr0/ks0
//   p1: read B[all]ks1 (4) + A[qr0]ks1 (4); stage A0(t+1)->S(t+1); MFMA qr0/ks1
//   p2: read A[qr1]ks0 (4);                 stage B0(t+2)->S(t);   MFMA qr1/ks0
//   p3: read A[qr1]ks1 (4);                 stage B1(t+2)->S(t);   MFMA qr1/ks1
//       + vmcnt(4) before the closing barrier.
// Region lifetimes (all-wave): S(t).B dies p1-end (staged p2/p3, >=1 barrier
// later); S(t).A halves die p3-end (staged next tile p0/p1). vmcnt ledger:
// entering tile t, 4 outstanding = B(t+1); tile issues 8; vmcnt(4)@p3 retires
// 8 oldest = B(t+1)+A(t+1) wait no -- retires B(t)?? see derivation: at p3,
// outstanding = B(t+1)[4 from t-1] + A(t+1)[4 from t p0/p1] + B(t+2)[4 from t
// p2/p3] = 12; vmcnt(4) retires 8 oldest = B(t+1)+A(t+1) -> everything tile
// t+1 reads has landed; barrier publishes. Deadlock-free: barriers wave-uniform.

#define STG(Lb, G, r0, kt)                                                   \
  gload16((G) + (long)((r0) + rl) * 1024 + (kt) * 64 + slswz,                \
          (Lb) + (r0) * 64 + tid * 8)

#define BRD(Bb, ksel)                                                        \
  _Pragma("unroll") for (int jj = 0; jj < 4; ++jj) {                         \
    const int idx = (wc * 64 + jj * 16 + fm) * 64 + (ksel)*32 + fk;          \
    bfr[jj][ksel] = *(const bf16x8*)((Bb) + (idx ^ swz));                    \
  }

#define ARD(Ab, qr, ksel)                                                    \
  _Pragma("unroll") for (int i = 0; i < 4; ++i) {                            \
    const int idx = (wr * 128 + (qr)*64 + i * 16 + fm) * 64 + (ksel)*32 + fk;\
    aC[i] = *(const bf16x8*)((Ab) + (idx ^ swz));                            \
  }

#define MM16(qr, ksel)                                                       \
  {                                                                          \
    __builtin_amdgcn_s_setprio(1);                                           \
    _Pragma("unroll") for (int i = 0; i < 4; ++i)                            \
    _Pragma("unroll") for (int j = 0; j < 4; ++j)                            \
        acc[(qr)*4 + i][j] = __builtin_amdgcn_mfma_f32_16x16x32_bf16(        \
            aC[i], bfr[j][ksel], acc[(qr)*4 + i][j], 0, 0, 0);               \
    __builtin_amdgcn_s_setprio(0);                                           \
  }

#define LGKM0 asm volatile("s_waitcnt lgkmcnt(0)" ::: "memory")
#define VM4 asm volatile("s_waitcnt vmcnt(4)" ::: "memory")
#define VM0 asm volatile("s_waitcnt vmcnt(0)" ::: "memory")
#define VMNONE (void)0
#define BAR __builtin_amdgcn_s_barrier()

#define TILE(Ab, Bb, Aoth, kt, SA, SB, VMW)                                  \
  {                                                                          \
    /* p0 */                                                                 \
    BRD(Bb, 0); ARD(Ab, 0, 0);                                               \
    if (SA) { STG(Aoth, Ag, 128, (kt) + 1); STG(Aoth, Ag, 192, (kt) + 1); }  \
    MM16(0, 0); LGKM0; BAR;                                                  \
    /* p1 */                                                                 \
    BRD(Bb, 1); ARD(Ab, 0, 1);                                               \
    if (SA) { STG(Aoth, Ag, 0, (kt) + 1); STG(Aoth, Ag, 64, (kt) + 1); }     \
    MM16(0, 1); LGKM0; BAR;                                                  \
    /* p2 */                                                                 \
    ARD(Ab, 1, 0);                                                           \
    if (SB) { STG(Bb, Bg, 0, (kt) + 2); STG(Bb, Bg, 64, (kt) + 2); }         \
    MM16(1, 0); LGKM0; BAR;                                                  \
    /* p3 */                                                                 \
    ARD(Ab, 1, 1);                                                           \
    if (SB) { STG(Bb, Bg, 128, (kt) + 2); STG(Bb, Bg, 192, (kt) + 2); }      \
    MM16(1, 1); LGKM0; VMW; BAR;                                             \
  }

template <int MODE>
__global__ __launch_bounds__(512, 2) void gemm256(const u16* __restrict__ A,
                                                  const u16* __restrict__ B,
                                                  void* __restrict__ C,
                                                  const float* __restrict__ bias) {
  __shared__ u16 As0[16384];
  __shared__ u16 As1[16384];
  __shared__ u16 Bs0[16384];
  __shared__ u16 Bs1[16384];
  const int tid = threadIdx.x;
  const int lane = tid & 63;
  const int wave = tid >> 6;
  const int wr = wave >> 2;  // 0..1 -> rows [wr*128, +128)
  const int wc = wave & 3;   // 0..3 -> cols [wc*64, +64)
  const int m0 = blockIdx.y * 256;
  const int n0 = blockIdx.x * 256;

  long aoff, boff, coff;
  if (MODE == 0) {
    int w = blockIdx.z >> 3;
    int b = blockIdx.z & 7;
    aoff = (long)w * 1048576;
    boff = (long)b * 4194304;
    coff = (long)blockIdx.z * 4194304;
  } else {
    aoff = (long)blockIdx.z * 4194304;
    boff = 0;
    coff = (long)blockIdx.z * 4194304;
  }
  const u16* Ag = A + aoff + (long)m0 * 1024;
  const u16* Bg = B + boff + (long)n0 * 1024;

  // staging decomposition: one STG = 512 lanes x 16B = 64 rows; per-thread
  // row rl, linear lds slot (tid&7); global slot pre-swizzled by row.
  const int rl = tid >> 3;
  const int slswz = ((tid & 7) ^ (rl & 7)) * 8;
  // fragment read decomposition
  const int fm = lane & 15;
  const int fk = (lane >> 4) << 3;
  const int swz = (fm & 7) << 3;  // u16-idx XOR; row&7 == fm&7 for all rows used

  f32x4 acc[8][4];
  const f32x4 z4 = {0.f, 0.f, 0.f, 0.f};
#pragma unroll
  for (int i = 0; i < 8; i++)
#pragma unroll
    for (int j = 0; j < 4; j++) acc[i][j] = z4;

  bf16x8 aC[4], bfr[4][2];

  // prologue: tile0 complete (8 loads) + tile1 B (4 loads); vmcnt(4) retires
  // tile0's 8, leaving B(1)x4 in flight = steady-state entry invariant.
  STG(Bs0, Bg, 0, 0);   STG(Bs0, Bg, 64, 0);
  STG(Bs0, Bg, 128, 0); STG(Bs0, Bg, 192, 0);
  STG(As0, Ag, 128, 0); STG(As0, Ag, 192, 0);
  STG(As0, Ag, 0, 0);   STG(As0, Ag, 64, 0);
  STG(Bs1, Bg, 0, 1);   STG(Bs1, Bg, 64, 1);
  STG(Bs1, Bg, 128, 1); STG(Bs1, Bg, 192, 1);
  VM4;
  BAR;

#pragma unroll 1
  for (int it = 0; it < 7; ++it) {
    TILE(As0, Bs0, As1, 2 * it, true, true, VM4);
    TILE(As1, Bs1, As0, 2 * it + 1, true, true, VM4);
  }
  TILE(As0, Bs0, As1, 14, true, false, VM0);   // stages A(15) only; drain
  TILE(As1, Bs1, As0, 15, false, false, VMNONE);

  // epilogue
  const int rq = (lane >> 4) * 4;
  const int mBase = m0 + wr * 128;
  const int nBase = n0 + wc * 64;
  if (MODE == 1) {
    float* Cf = (float*)C + coff;
#pragma unroll
    for (int jj = 0; jj < 4; ++jj) {
      float bv = bias[nBase + jj * 16 + fm];
#pragma unroll
      for (int i = 0; i < 8; ++i)
#pragma unroll
        for (int r = 0; r < 4; ++r) {
          int m = mBase + i * 16 + rq + r;
          int n = nBase + jj * 16 + fm;
          Cf[(long)m * 1024 + n] = acc[i][jj][r] + bv;
        }
    }
  } else {
    const int ldc = (MODE == 0) ? 4096 : 1024;
    u16* Cb = (u16*)C + coff;
#pragma unroll
    for (int i = 0; i < 8; ++i)
#pragma unroll
      for (int jj = 0; jj < 4; ++jj)
#pragma unroll
        for (int r = 0; r < 4; ++r) {
          int m = mBase + i * 16 + rq + r;
          int n = nBase + jj * 16 + fm;
          Cb[(long)m * ldc + n] = f2bf(acc[i][jj][r]);
        }
  }
}

// ---------------- attn partial: per (bh, kslice-of-4) block; 16 wave-slices ----------------
// Each wave owns 256 k, computes full 64x64 partial S + row sumsq, writes to ws.
__global__ __launch_bounds__(256) void attn_partial(const u16* __restrict__ qk,
                                                    float* __restrict__ attnP,
                                                    float* __restrict__ nsqP) {
  const int bh = blockIdx.x;
  const int b = bh >> 4, h = bh & 15;
  const int tid = threadIdx.x, lane = tid & 63, wave = tid >> 6;
  const int sl = blockIdx.y * 4 + wave;  // 0..15
  const u16* Qg = qk + (long)b * 4194304 + (long)h * 64 * 4096;
  const u16* Kg = Qg + 33554432L;

  const int fm = lane & 15;
  const long kbase = (long)sl * 256 + (lane >> 4) * 8;

  f32x4 acc[4][4];
  const f32x4 z4 = {0.f, 0.f, 0.f, 0.f};
#pragma unroll
  for (int i = 0; i < 4; i++)
#pragma unroll
    for (int j = 0; j < 4; j++) acc[i][j] = z4;
  float sk[4] = {0.f, 0.f, 0.f, 0.f}, sq[4] = {0.f, 0.f, 0.f, 0.f};

  for (int kt = 0; kt < 256; kt += 32) {
    bf16x8 ak[4], aq[4];
#pragma unroll
    for (int i = 0; i < 4; i++) {
      ak[i] = *(const bf16x8*)(Kg + (long)(i * 16 + fm) * 4096 + kbase + kt);
      aq[i] = *(const bf16x8*)(Qg + (long)(i * 16 + fm) * 4096 + kbase + kt);
    }
#pragma unroll
    for (int i = 0; i < 4; i++) {
      const u16x8 kv = (u16x8)ak[i], qv = (u16x8)aq[i];
#pragma unroll
      for (int e = 0; e < 8; e++) {
        float fkk = bf2f(kv[e]); sk[i] += fkk * fkk;
        float fq = bf2f(qv[e]);  sq[i] += fq * fq;
      }
    }
#pragma unroll
    for (int i = 0; i < 4; i++)
#pragma unroll
      for (int j = 0; j < 4; j++)
        acc[i][j] = __builtin_amdgcn_mfma_f32_16x16x32_bf16(ak[i], aq[j],
                                                            acc[i][j], 0, 0, 0);
  }

#pragma unroll
  for (int i = 0; i < 4; i++) {  // fold the 4 k-chunk lane groups
    sk[i] += __shfl_xor(sk[i], 16); sk[i] += __shfl_xor(sk[i], 32);
    sq[i] += __shfl_xor(sq[i], 16); sq[i] += __shfl_xor(sq[i], 32);
  }
  float* np = nsqP + ((long)sl * 128 + bh) * 128;
  if (lane < 16) {
#pragma unroll
    for (int i = 0; i < 4; i++) {
      np[i * 16 + lane] = sk[i];
      np[64 + i * 16 + lane] = sq[i];
    }
  }
  float* sp = attnP + ((long)sl * 128 + bh) * 4096;
  const int rq = (lane >> 4) * 4;
#pragma unroll
  for (int i = 0; i < 4; i++)
#pragma unroll
    for (int j = 0; j < 4; j++)
#pragma unroll
      for (int r = 0; r < 4; r++)
        sp[(i * 16 + rq + r) * 64 + j * 16 + fm] = acc[i][j][r];
}

// ---------------- finalize: sum 16 partials, norms, softmax -> bf16 ----------------
// grid (128 bh, 2 d-halves) x 256 threads; thread owns (d, 8-wide e-chunk);
// softmax reduce across the 8 lanes sharing d via shfl_xor. Coalesced loads.
__global__ __launch_bounds__(256) void attn_finalize(const float* __restrict__ attnP,
                                                     const float* __restrict__ nsqP,
                                                     const float* __restrict__ scale,
                                                     u16* __restrict__ attnb) {
  const int bh = blockIdx.x;
  const int dz = blockIdx.y;  // d-half
  const int h = bh & 15;
  const int tid = threadIdx.x;
  __shared__ float rn[2][64];
  if (tid < 128) {
    int which = tid >> 6, row = tid & 63;
    float s = 0.f;
#pragma unroll
    for (int sl = 0; sl < 16; sl++)
      s += nsqP[((long)sl * 128 + bh) * 128 + which * 64 + row];
    rn[which][row] = 1.0f / fmaxf(sqrtf(s), 1e-12f);  // F.normalize eps
  }
  __syncthreads();
  const int d = dz * 32 + (tid >> 3);
  const int q8 = tid & 3 ? (tid & 7) : (tid & 7);  // e-chunk index 0..7
  float row[8];
#pragma unroll
  for (int e = 0; e < 8; e++) row[e] = 0.f;
  for (int sl = 0; sl < 16; sl++) {
    const float4* p = (const float4*)(attnP + ((long)sl * 128 + bh) * 4096 +
                                      d * 64 + (tid & 7) * 8);
    float4 v0 = p[0], v1 = p[1];
    row[0] += v0.x; row[1] += v0.y; row[2] += v0.z; row[3] += v0.w;
    row[4] += v1.x; row[5] += v1.y; row[6] += v1.z; row[7] += v1.w;
  }
  const float rk = rn[0][d] * scale[h];
  float mx = -1e30f;
#pragma unroll
  for (int e = 0; e < 8; e++) {
    row[e] = row[e] * rk * rn[1][(tid & 7) * 8 + e];
    mx = fmaxf(mx, row[e]);
  }
  mx = fmaxf(mx, __shfl_xor(mx, 1));
  mx = fmaxf(mx, __shfl_xor(mx, 2));
  mx = fmaxf(mx, __shfl_xor(mx, 4));
  float sum = 0.f;
#pragma unroll
  for (int e = 0; e < 8; e++) {
    row[e] = __expf(row[e] - mx);
    sum += row[e];
  }
  sum += __shfl_xor(sum, 1);
  sum += __shfl_xor(sum, 2);
  sum += __shfl_xor(sum, 4);
  float inv = 1.0f / sum;
  u16x8 o;
#pragma unroll
  for (int e = 0; e < 8; e++) o[e] = f2bf(row[e] * inv);
  *(u16x8*)(attnb + (long)bh * 4096 + d * 64 + (tid & 7) * 8) = o;
  (void)q8;
}

// ---------------- av: out[d,n] = sum_e attn[d,e]*Vt[n,e], MFMA K=64 ----------------
__global__ __launch_bounds__(256) void av_mfma(const u16* __restrict__ attnb,
                                               const u16* __restrict__ vt,
                                               u16* __restrict__ outb) {
  const int bh = blockIdx.y;
  const int b = bh >> 4, h = bh & 15;
  const int n0 = blockIdx.x * 256;
  const int tid = threadIdx.x, lane = tid & 63, wave = tid >> 6;
  __shared__ u16 As[64 * 72];  // attn [d][e], pad 64->72 (row stride 144B)
  {
    const u16* src = attnb + (long)bh * 4096 + (tid >> 2) * 64 + (tid & 3) * 16;
    u16x8 v0 = *(const u16x8*)src;
    u16x8 v1 = *(const u16x8*)(src + 8);
    u16* dst = As + (tid >> 2) * 72 + (tid & 3) * 16;
    *(u16x8*)dst = v0;
    *(u16x8*)(dst + 8) = v1;
  }
  __syncthreads();
  const int fm = lane & 15;
  const int fe = (lane >> 4) * 8;
  const u16* Vg = vt + (long)b * 4194304 + h * 64 + fe;

  f32x4 acc[4][4];
  const f32x4 z4 = {0.f, 0.f, 0.f, 0.f};
#pragma unroll
  for (int i = 0; i < 4; i++)
#pragma unroll
    for (int j = 0; j < 4; j++) acc[i][j] = z4;

  bf16x8 af[4][2];
#pragma unroll
  for (int i = 0; i < 4; i++)
#pragma unroll
    for (int ks = 0; ks < 2; ks++)
      af[i][ks] = *(const bf16x8*)&As[(i * 16 + fm) * 72 + fe + ks * 32];

#pragma unroll
  for (int ks = 0; ks < 2; ks++)
#pragma unroll
    for (int j = 0; j < 4; j++) {
      int n = n0 + wave * 64 + j * 16 + fm;
      bf16x8 bf = *(const bf16x8*)(Vg + (long)n * 1024 + ks * 32);
#pragma unroll
      for (int i = 0; i < 4; i++)
        acc[i][j] = __builtin_amdgcn_mfma_f32_16x16x32_bf16(af[i][ks], bf,
                                                            acc[i][j], 0, 0, 0);
    }

  const int rq = (lane >> 4) * 4;
  u16* Ob = outb + ((long)b * 1024 + h * 64) * 4096;
#pragma unroll
  for (int i = 0; i < 4; i++)
#pragma unroll
    for (int j = 0; j < 4; j++)
#pragma unroll
      for (int r = 0; r < 4; r++) {
        int d = i * 16 + rq + r;
        int n = n0 + wave * 64 + j * 16 + fm;
        Ob[(long)d * 4096 + n] = f2bf(acc[i][j][r]);
      }
}

extern "C" void kernel_launch(void* const* d_in, const int* in_sizes, int n_in,
                              void* d_out, int out_size, void* d_ws, size_t ws_size,
                              hipStream_t stream) {
  const float* x = (const float*)d_in[0];
  const float* Wq = (const float*)d_in[1];
  const float* Wk = (const float*)d_in[2];
  const float* Wv = (const float*)d_in[3];
  const float* scale = (const float*)d_in[4];
  const float* Wo = (const float*)d_in[5];
  const float* bo = (const float*)d_in[6];
  float* out = (float*)d_out;

  u16* xbf = (u16*)d_ws;                     // 33,554,432
  u16* wbf = xbf + 33554432;                 //  4,194,304
  u16* qk = wbf + 4194304;                   // 67,108,864 (Q then K, ch-major)
  u16* vt = qk + 67108864;                   // 33,554,432 (token-major V)
  float* attnP = (float*)(vt + 33554432);    //  8,388,608 floats
  float* nsqP = attnP + 8388608;             //    262,144 floats
  u16* attnb = (u16*)(nsqP + 262144);        //    524,288
  u16* outb = qk;                            // alias: Q,K dead after attn_partial

  cast_kernel<<<32768, 256, 0, stream>>>((const float4*)x, (const float4*)Wq,
                                         (const float4*)Wk, (const float4*)Wv,
                                         (const float4*)Wo, (u16x4*)xbf,
                                         (u16x4*)wbf);
  gemm256<0><<<dim3(16, 4, 16), 512, 0, stream>>>(wbf, xbf, (void*)qk, nullptr);
  gemm256<2><<<dim3(4, 16, 8), 512, 0, stream>>>(xbf, wbf + 2 * 1048576,
                                                 (void*)vt, nullptr);
  attn_partial<<<dim3(128, 4), 256, 0, stream>>>(qk, attnP, nsqP);
  attn_finalize<<<dim3(128, 2), 256, 0, stream>>>(attnP, nsqP, scale, attnb);
  av_mfma<<<dim3(16, 128), 256, 0, stream>>>(attnb, vt, outb);
  gemm256<1><<<dim3(4, 16, 8), 512, 0, stream>>>(outb, wbf + 3 * 1048576,
                                                 (void*)out, bo);
}